// Round 1
// baseline (259.376 us; speedup 1.0000x reference)
//
#include <hip/hip_runtime.h>

typedef __attribute__((ext_vector_type(8))) short bf16x8;
typedef __attribute__((ext_vector_type(4))) float f32x4;
typedef unsigned short u16;
typedef unsigned int u32;

#define DEV static __device__ __forceinline__

DEV u16 f2bf(float f) {
  u32 u = __float_as_uint(f);
  u += 0x7FFFu + ((u >> 16) & 1u);
  return (u16)(u >> 16);
}
DEV float bf2f(u16 h) { return __uint_as_float(((u32)h) << 16); }

DEV void gload16(const void* g, void* l) {
  __builtin_amdgcn_global_load_lds((const __attribute__((address_space(1))) void*)g,
                                   (__attribute__((address_space(3))) void*)l, 16, 0, 0);
}

#define MFMA16(a, b, c) __builtin_amdgcn_mfma_f32_16x16x32_bf16((a), (b), (c), 0, 0, 0)

// ---------------- fp32 -> bf16 convert (x) ----------------
__global__ __launch_bounds__(256) void k_cvt_bf16(const float* __restrict__ in,
                                                  u16* __restrict__ out, int n8) {
  int i = blockIdx.x * 256 + threadIdx.x;
  if (i >= n8) return;
  const f32x4* p = (const f32x4*)(in + (size_t)i * 8);
  f32x4 a = p[0], b = p[1];
  bf16x8 o;
  o[0] = (short)f2bf(a[0]); o[1] = (short)f2bf(a[1]);
  o[2] = (short)f2bf(a[2]); o[3] = (short)f2bf(a[3]);
  o[4] = (short)f2bf(b[0]); o[5] = (short)f2bf(b[1]);
  o[6] = (short)f2bf(b[2]); o[7] = (short)f2bf(b[3]);
  *(bf16x8*)(out + (size_t)i * 8) = o;
}

// ---------------- fp32 [rows][cols] -> bf16 [cols][rows] ----------------
__global__ __launch_bounds__(256) void k_transpose_bf16(const float* __restrict__ src,
                                                        u16* __restrict__ dst,
                                                        int rows, int cols) {
  __shared__ u16 lds[64][72];
  int t = threadIdx.x;
  int r0 = blockIdx.y * 64, c0 = blockIdx.x * 64;
  int r = t >> 2, cq = (t & 3) << 4;
  const float* s = src + (size_t)(r0 + r) * cols + c0 + cq;
#pragma unroll
  for (int i = 0; i < 16; i += 4) {
    f32x4 v = *(const f32x4*)(s + i);
    lds[r][cq + i + 0] = f2bf(v[0]);
    lds[r][cq + i + 1] = f2bf(v[1]);
    lds[r][cq + i + 2] = f2bf(v[2]);
    lds[r][cq + i + 3] = f2bf(v[3]);
  }
  __syncthreads();
  int c = t >> 2, rq = (t & 3) << 4;
  bf16x8 o0, o1;
#pragma unroll
  for (int i = 0; i < 8; ++i) o0[i] = (short)lds[rq + i][c];
#pragma unroll
  for (int i = 0; i < 8; ++i) o1[i] = (short)lds[rq + 8 + i][c];
  u16* d = dst + (size_t)(c0 + c) * rows + r0 + rq;
  *(bf16x8*)d = o0;
  *(bf16x8*)(d + 8) = o1;
}

// ---------------- bf16 GEMM: C[M][N] = A[M][K] * Bt[N][K]^T ----------------
template <bool OUT_BF16, bool HAS_BIAS>
__global__ __launch_bounds__(256) void k_gemm_bt(const u16* __restrict__ A,
                                                 const u16* __restrict__ Bt,
                                                 void* __restrict__ Cout,
                                                 const float* __restrict__ bias,
                                                 int M, int N, int K) {
  __shared__ __align__(16) u16 lsA[128 * 32];
  __shared__ __align__(16) u16 lsB[128 * 32];
  int tid = threadIdx.x;
  int lane = tid & 63, wave = tid >> 6;
  int wr = (wave >> 1) * 64, wc = (wave & 1) * 64;
  int bm = blockIdx.y * 128, bn = blockIdx.x * 128;

  f32x4 acc[4][4] = {};

  const u16* aSrc[2]; u16* aDst[2];
  const u16* bSrc[2]; u16* bDst[2];
#pragma unroll
  for (int j = 0; j < 2; ++j) {
    int s = wave * 128 + j * 64 + lane;
    int row = s >> 2, chunk = s & 3;
    int g = chunk ^ ((row >> 1) & 3);
    aSrc[j] = A + (size_t)(bm + row) * K + g * 8;
    bSrc[j] = Bt + (size_t)(bn + row) * K + g * 8;
    aDst[j] = &lsA[(wave * 128 + j * 64) * 8];
    bDst[j] = &lsB[(wave * 128 + j * 64) * 8];
  }

  for (int k0 = 0; k0 < K; k0 += 32) {
    __syncthreads();
    gload16(aSrc[0] + k0, aDst[0]);
    gload16(aSrc[1] + k0, aDst[1]);
    gload16(bSrc[0] + k0, bDst[0]);
    gload16(bSrc[1] + k0, bDst[1]);
    __syncthreads();
    bf16x8 af[4], bfr[4];
#pragma unroll
    for (int m = 0; m < 4; ++m) {
      int r = wr + m * 16 + (lane & 15);
      int p = (lane >> 4) ^ ((r >> 1) & 3);
      af[m] = *(const bf16x8*)&lsA[r * 32 + p * 8];
    }
#pragma unroll
    for (int n = 0; n < 4; ++n) {
      int r = wc + n * 16 + (lane & 15);
      int p = (lane >> 4) ^ ((r >> 1) & 3);
      bfr[n] = *(const bf16x8*)&lsB[r * 32 + p * 8];
    }
#pragma unroll
    for (int m = 0; m < 4; ++m)
#pragma unroll
      for (int n = 0; n < 4; ++n)
        acc[m][n] = MFMA16(af[m], bfr[n], acc[m][n]);
  }

#pragma unroll
  for (int m = 0; m < 4; ++m) {
    int row = bm + wr + m * 16 + ((lane >> 4) << 2);
#pragma unroll
    for (int n = 0; n < 4; ++n) {
      int col = bn + wc + n * 16 + (lane & 15);
#pragma unroll
      for (int j = 0; j < 4; ++j) {
        if (OUT_BF16) {
          ((u16*)Cout)[(size_t)(row + j) * N + col] = f2bf(acc[m][n][j]);
        } else {
          float bb = HAS_BIAS ? bias[col] : 0.f;
          ((float*)Cout)[(size_t)(row + j) * N + col] = acc[m][n][j] + bb;
        }
      }
    }
  }
}

// ---------------- repack: normalize q,k (fold scale into q), transpose v ----------------
__global__ __launch_bounds__(256) void k_repack(const u16* __restrict__ QKV,
                                                const float* __restrict__ logit_scale,
                                                u16* __restrict__ Qn, u16* __restrict__ Kn,
                                                u16* __restrict__ Vt) {
  int nt = blockIdx.x;  // 0..31 (64-row tile)
  int h = blockIdx.y;   // 0..15
  int b = blockIdx.z;   // 0..1
  int tid = threadIdx.x;
  int lane = tid & 63, wave = tid >> 6;
  int bh = b * 16 + h;
  float scale = __expf(fminf(logit_scale[h], 4.6051701859880914f));

#pragma unroll 1
  for (int i = 0; i < 16; ++i) {
    int n = nt * 64 + wave * 16 + i;
    size_t off = ((size_t)(b * 2048 + n)) * 3072 + h * 64 + lane;
    float q = bf2f(QKV[off]);
    float k = bf2f(QKV[off + 1024]);
    float sq = q * q, sk = k * k;
#pragma unroll
    for (int d = 1; d < 64; d <<= 1) {
      sq += __shfl_xor(sq, d, 64);
      sk += __shfl_xor(sk, d, 64);
    }
    float rq = scale / fmaxf(sqrtf(sq), 1e-12f);
    float rk = 1.0f / fmaxf(sqrtf(sk), 1e-12f);
    size_t o2 = ((size_t)bh * 2048 + n) * 64 + lane;
    Qn[o2] = f2bf(q * rq);
    Kn[o2] = f2bf(k * rk);
  }

  // V transpose via LDS
  __shared__ u16 lds[64][72];
  int r = tid >> 2, cq = (tid & 3) << 4;
  size_t voff = ((size_t)(b * 2048 + nt * 64 + r)) * 3072 + 2048 + h * 64 + cq;
  *(bf16x8*)&lds[r][cq] = *(const bf16x8*)&QKV[voff];
  *(bf16x8*)&lds[r][cq + 8] = *(const bf16x8*)&QKV[voff + 8];
  __syncthreads();
  int d = tid >> 2, nq = (tid & 3) << 4;
  bf16x8 o0, o1;
#pragma unroll
  for (int i = 0; i < 8; ++i) o0[i] = (short)lds[nq + i][d];
#pragma unroll
  for (int i = 0; i < 8; ++i) o1[i] = (short)lds[nq + 8 + i][d];
  u16* vd = Vt + ((size_t)bh * 64 + d) * 2048 + nt * 64 + nq;
  *(bf16x8*)vd = o0;
  *(bf16x8*)(vd + 8) = o1;
}

// ---------------- flash attention ----------------
__global__ __launch_bounds__(256) void k_flash(const u16* __restrict__ Qn,
                                               const u16* __restrict__ Kn,
                                               const u16* __restrict__ Vt,
                                               u16* __restrict__ AO) {
  __shared__ __align__(16) u16 lsK[128 * 64];
  __shared__ __align__(16) u16 lsV[64 * 128];
  __shared__ __align__(16) u16 lsP[4][32 * 128];
  int tid = threadIdx.x, lane = tid & 63, wave = tid >> 6;
  int bh = blockIdx.y, b = bh >> 4, h = bh & 15;
  int q0 = blockIdx.x * 128;
  const u16* Q = Qn + (size_t)bh * 2048 * 64;
  const u16* Kb = Kn + (size_t)bh * 2048 * 64;
  const u16* Vb = Vt + (size_t)bh * 64 * 2048;

  int qw = q0 + wave * 32;
  bf16x8 qf[2][2];
#pragma unroll
  for (int m = 0; m < 2; ++m)
#pragma unroll
    for (int kk = 0; kk < 2; ++kk)
      qf[m][kk] = *(const bf16x8*)&Q[(size_t)(qw + m * 16 + (lane & 15)) * 64 +
                                     kk * 32 + ((lane >> 4) * 8)];

  f32x4 o[2][4] = {};
  float mrow[2][4], lrow[2][4];
#pragma unroll
  for (int m = 0; m < 2; ++m)
#pragma unroll
    for (int j = 0; j < 4; ++j) { mrow[m][j] = -1e30f; lrow[m][j] = 0.f; }

  const u16* kSrc[4]; u16* kDst[4];
  const u16* vSrc[4]; u16* vDst[4];
#pragma unroll
  for (int j = 0; j < 4; ++j) {
    int s = (wave * 4 + j) * 64 + lane;
    {
      int row = s >> 3, ch = s & 7, g = ch ^ (row & 7);
      kSrc[j] = Kb + (size_t)row * 64 + g * 8;
      kDst[j] = &lsK[(wave * 4 + j) * 512];
    }
    {
      int row = s >> 4, ch = s & 15, g = ch ^ (row & 15);
      vSrc[j] = Vb + (size_t)row * 2048 + g * 8;
      vDst[j] = &lsV[(wave * 4 + j) * 512];
    }
  }

  for (int t = 0; t < 16; ++t) {
    int kv0 = t * 128;
    __syncthreads();
#pragma unroll
    for (int j = 0; j < 4; ++j) {
      gload16(kSrc[j] + (size_t)kv0 * 64, kDst[j]);
      gload16(vSrc[j] + kv0, vDst[j]);
    }
    __syncthreads();

    // S = Q K^T (rows = q, cols = kv)
    f32x4 sc[2][8] = {};
#pragma unroll
    for (int kk = 0; kk < 2; ++kk) {
#pragma unroll
      for (int n = 0; n < 8; ++n) {
        int kvr = n * 16 + (lane & 15);
        int p = (kk * 4 + (lane >> 4)) ^ (kvr & 7);
        bf16x8 kb = *(const bf16x8*)&lsK[kvr * 64 + p * 8];
        sc[0][n] = MFMA16(qf[0][kk], kb, sc[0][n]);
        sc[1][n] = MFMA16(qf[1][kk], kb, sc[1][n]);
      }
    }

    // online softmax (rows owned: (lane>>4)*4 + j)
    float corr[2][4];
#pragma unroll
    for (int m = 0; m < 2; ++m)
#pragma unroll
      for (int j = 0; j < 4; ++j) {
        float mx = sc[m][0][j];
#pragma unroll
        for (int n = 1; n < 8; ++n) mx = fmaxf(mx, sc[m][n][j]);
#pragma unroll
        for (int d = 1; d < 16; d <<= 1) mx = fmaxf(mx, __shfl_xor(mx, d, 64));
        float mnew = fmaxf(mrow[m][j], mx);
        float c = __expf(mrow[m][j] - mnew);
        float rs = 0.f;
#pragma unroll
        for (int n = 0; n < 8; ++n) {
          float pv = __expf(sc[m][n][j] - mnew);
          sc[m][n][j] = pv;
          rs += pv;
        }
#pragma unroll
        for (int d = 1; d < 16; d <<= 1) rs += __shfl_xor(rs, d, 64);
        lrow[m][j] = lrow[m][j] * c + rs;
        mrow[m][j] = mnew;
        corr[m][j] = c;
      }
#pragma unroll
    for (int m = 0; m < 2; ++m)
#pragma unroll
      for (int dn = 0; dn < 4; ++dn)
#pragma unroll
        for (int j = 0; j < 4; ++j) o[m][dn][j] *= corr[m][j];

    // write P (bf16) to per-wave LDS in A-fragment-friendly swizzled layout
    u16* Pw = &lsP[wave][0];
#pragma unroll
    for (int m = 0; m < 2; ++m)
#pragma unroll
      for (int n = 0; n < 8; ++n)
#pragma unroll
        for (int j = 0; j < 4; ++j) {
          int pr = m * 16 + ((lane >> 4) << 2) + j;
          int col = n * 16 + (lane & 15);
          int ch = col >> 3;
          int pp = ch ^ (pr & 15);
          Pw[pr * 128 + pp * 8 + (col & 7)] = f2bf(sc[m][n][j]);
        }

    // O += P V
#pragma unroll
    for (int kk = 0; kk < 4; ++kk) {
      bf16x8 pa[2];
#pragma unroll
      for (int m = 0; m < 2; ++m) {
        int pr = m * 16 + (lane & 15);
        int pp = (kk * 4 + (lane >> 4)) ^ (pr & 15);
        pa[m] = *(const bf16x8*)&Pw[pr * 128 + pp * 8];
      }
#pragma unroll
      for (int dn = 0; dn < 4; ++dn) {
        int dr = dn * 16 + (lane & 15);
        int pp = (kk * 4 + (lane >> 4)) ^ (dr & 15);
        bf16x8 vb = *(const bf16x8*)&lsV[dr * 128 + pp * 8];
#pragma unroll
        for (int m = 0; m < 2; ++m) o[m][dn] = MFMA16(pa[m], vb, o[m][dn]);
      }
    }
  }

  // epilogue: O /= l, write to AO[b*2048+q][h*64+d]
#pragma unroll
  for (int m = 0; m < 2; ++m)
#pragma unroll
    for (int j = 0; j < 4; ++j) {
      float inv = 1.0f / lrow[m][j];
      int qr = qw + m * 16 + ((lane >> 4) << 2) + j;
      size_t base = ((size_t)(b * 2048 + qr)) * 1024 + h * 64;
#pragma unroll
      for (int dn = 0; dn < 4; ++dn)
        AO[base + dn * 16 + (lane & 15)] = f2bf(o[m][dn][j] * inv);
    }
}

// ---------------- host ----------------
extern "C" void kernel_launch(void* const* d_in, const int* in_sizes, int n_in,
                              void* d_out, int out_size, void* d_ws, size_t ws_size,
                              hipStream_t stream) {
  const float* x = (const float*)d_in[0];
  const float* w_qkv = (const float*)d_in[1];
  const float* w_out = (const float*)d_in[2];
  const float* b_out = (const float*)d_in[3];
  const float* logit_scale = (const float*)d_in[4];

  char* ws = (char*)d_ws;
  u16* Xbf   = (u16*)(ws);                   // 8 MB  [4096][1024]
  u16* Wqkvt = (u16*)(ws + (8ll << 20));     // 6 MB  [3072][1024]
  u16* Woutt = (u16*)(ws + (14ll << 20));    // 2 MB  [1024][1024]
  u16* QKV   = (u16*)(ws + (16ll << 20));    // 24 MB [4096][3072]
  u16* Qn    = (u16*)(ws + (40ll << 20));    // 8 MB  [2][16][2048][64]
  u16* Kn    = (u16*)(ws + (48ll << 20));    // 8 MB
  u16* Vt    = (u16*)(ws + (56ll << 20));    // 8 MB  [2][16][64][2048]
  u16* AO    = Xbf;                          // reuse x-bf16 region [4096][1024]
  float* out = (float*)d_out;

  k_cvt_bf16<<<2048, 256, 0, stream>>>(x, Xbf, 524288);
  k_transpose_bf16<<<dim3(48, 16), 256, 0, stream>>>(w_qkv, Wqkvt, 1024, 3072);
  k_transpose_bf16<<<dim3(16, 16), 256, 0, stream>>>(w_out, Woutt, 1024, 1024);
  k_gemm_bt<true, false><<<dim3(24, 32), 256, 0, stream>>>(Xbf, Wqkvt, QKV, nullptr,
                                                           4096, 3072, 1024);
  k_repack<<<dim3(32, 16, 2), 256, 0, stream>>>(QKV, logit_scale, Qn, Kn, Vt);
  k_flash<<<dim3(16, 32), 256, 0, stream>>>(Qn, Kn, Vt, AO);
  k_gemm_bt<false, true><<<dim3(8, 32), 256, 0, stream>>>(AO, Woutt, out, b_out,
                                                          4096, 1024, 1024);
}

// Round 2
// 147.804 us; speedup vs baseline: 1.7549x; 1.7549x over previous
//
#include <hip/hip_runtime.h>

typedef __attribute__((ext_vector_type(8))) short bf16x8;
typedef __attribute__((ext_vector_type(4))) float f32x4;
typedef __attribute__((ext_vector_type(16))) float f32x16;
typedef unsigned short u16;
typedef unsigned int u32;
typedef __attribute__((ext_vector_type(4))) unsigned int u32x4;

#define DEV static __device__ __forceinline__

DEV u16 f2bf(float f) {
  u32 u = __float_as_uint(f);
  u += 0x7FFFu + ((u >> 16) & 1u);
  return (u16)(u >> 16);
}
DEV float bf2f(u16 h) { return __uint_as_float(((u32)h) << 16); }

DEV void gload16(const void* g, void* l) {
  __builtin_amdgcn_global_load_lds((const __attribute__((address_space(1))) void*)g,
                                   (__attribute__((address_space(3))) void*)l, 16, 0, 0);
}

#define MFMA16(a, b, c) __builtin_amdgcn_mfma_f32_16x16x32_bf16((a), (b), (c), 0, 0, 0)
#define MFMA32(a, b, c) __builtin_amdgcn_mfma_f32_32x32x16_bf16((a), (b), (c), 0, 0, 0)

DEV u32 cvtpk(float lo, float hi) {
  u32 r;
  asm("v_cvt_pk_bf16_f32 %0, %1, %2" : "=v"(r) : "v"(lo), "v"(hi));
  return r;
}
DEV void plswap(u32& a, u32& b) {
  asm volatile("v_permlane32_swap_b32 %0, %1" : "+v"(a), "+v"(b));
}
DEV bf16x8 asbf(u32x4 v) {
  union { u32x4 u; bf16x8 b; } x;
  x.u = v;
  return x.b;
}

// ---------------- fp32 -> bf16 convert (x) ----------------
__global__ __launch_bounds__(256) void k_cvt_bf16(const float* __restrict__ in,
                                                  u16* __restrict__ out, int n8) {
  int i = blockIdx.x * 256 + threadIdx.x;
  if (i >= n8) return;
  const f32x4* p = (const f32x4*)(in + (size_t)i * 8);
  f32x4 a = p[0], b = p[1];
  bf16x8 o;
  o[0] = (short)f2bf(a[0]); o[1] = (short)f2bf(a[1]);
  o[2] = (short)f2bf(a[2]); o[3] = (short)f2bf(a[3]);
  o[4] = (short)f2bf(b[0]); o[5] = (short)f2bf(b[1]);
  o[6] = (short)f2bf(b[2]); o[7] = (short)f2bf(b[3]);
  *(bf16x8*)(out + (size_t)i * 8) = o;
}

// ---------------- fp32 [rows][cols] -> bf16 [cols][rows] ----------------
__global__ __launch_bounds__(256) void k_transpose_bf16(const float* __restrict__ src,
                                                        u16* __restrict__ dst,
                                                        int rows, int cols) {
  __shared__ u16 lds[64][72];
  int t = threadIdx.x;
  int r0 = blockIdx.y * 64, c0 = blockIdx.x * 64;
  int r = t >> 2, cq = (t & 3) << 4;
  const float* s = src + (size_t)(r0 + r) * cols + c0 + cq;
#pragma unroll
  for (int i = 0; i < 16; i += 4) {
    f32x4 v = *(const f32x4*)(s + i);
    lds[r][cq + i + 0] = f2bf(v[0]);
    lds[r][cq + i + 1] = f2bf(v[1]);
    lds[r][cq + i + 2] = f2bf(v[2]);
    lds[r][cq + i + 3] = f2bf(v[3]);
  }
  __syncthreads();
  int c = t >> 2, rq = (t & 3) << 4;
  bf16x8 o0, o1;
#pragma unroll
  for (int i = 0; i < 8; ++i) o0[i] = (short)lds[rq + i][c];
#pragma unroll
  for (int i = 0; i < 8; ++i) o1[i] = (short)lds[rq + 8 + i][c];
  u16* d = dst + (size_t)(c0 + c) * rows + r0 + rq;
  *(bf16x8*)d = o0;
  *(bf16x8*)(d + 8) = o1;
}

// ---------------- bf16 GEMM: C[M][N] = A[M][K] * Bt[N][K]^T ----------------
template <bool OUT_BF16, bool HAS_BIAS>
__global__ __launch_bounds__(256) void k_gemm_bt(const u16* __restrict__ A,
                                                 const u16* __restrict__ Bt,
                                                 void* __restrict__ Cout,
                                                 const float* __restrict__ bias,
                                                 int M, int N, int K) {
  __shared__ __align__(16) u16 lsA[128 * 32];
  __shared__ __align__(16) u16 lsB[128 * 32];
  int tid = threadIdx.x;
  int lane = tid & 63, wave = tid >> 6;
  int wr = (wave >> 1) * 64, wc = (wave & 1) * 64;
  int bm = blockIdx.y * 128, bn = blockIdx.x * 128;

  f32x4 acc[4][4] = {};

  const u16* aSrc[2]; u16* aDst[2];
  const u16* bSrc[2]; u16* bDst[2];
#pragma unroll
  for (int j = 0; j < 2; ++j) {
    int s = wave * 128 + j * 64 + lane;
    int row = s >> 2, chunk = s & 3;
    int g = chunk ^ ((row >> 1) & 3);
    aSrc[j] = A + (size_t)(bm + row) * K + g * 8;
    bSrc[j] = Bt + (size_t)(bn + row) * K + g * 8;
    aDst[j] = &lsA[(wave * 128 + j * 64) * 8];
    bDst[j] = &lsB[(wave * 128 + j * 64) * 8];
  }

  for (int k0 = 0; k0 < K; k0 += 32) {
    __syncthreads();
    gload16(aSrc[0] + k0, aDst[0]);
    gload16(aSrc[1] + k0, aDst[1]);
    gload16(bSrc[0] + k0, bDst[0]);
    gload16(bSrc[1] + k0, bDst[1]);
    __syncthreads();
    bf16x8 af[4], bfr[4];
#pragma unroll
    for (int m = 0; m < 4; ++m) {
      int r = wr + m * 16 + (lane & 15);
      int p = (lane >> 4) ^ ((r >> 1) & 3);
      af[m] = *(const bf16x8*)&lsA[r * 32 + p * 8];
    }
#pragma unroll
    for (int n = 0; n < 4; ++n) {
      int r = wc + n * 16 + (lane & 15);
      int p = (lane >> 4) ^ ((r >> 1) & 3);
      bfr[n] = *(const bf16x8*)&lsB[r * 32 + p * 8];
    }
#pragma unroll
    for (int m = 0; m < 4; ++m)
#pragma unroll
      for (int n = 0; n < 4; ++n)
        acc[m][n] = MFMA16(af[m], bfr[n], acc[m][n]);
  }

#pragma unroll
  for (int m = 0; m < 4; ++m) {
    int row = bm + wr + m * 16 + ((lane >> 4) << 2);
#pragma unroll
    for (int n = 0; n < 4; ++n) {
      int col = bn + wc + n * 16 + (lane & 15);
#pragma unroll
      for (int j = 0; j < 4; ++j) {
        if (OUT_BF16) {
          ((u16*)Cout)[(size_t)(row + j) * N + col] = f2bf(acc[m][n][j]);
        } else {
          float bb = HAS_BIAS ? bias[col] : 0.f;
          ((float*)Cout)[(size_t)(row + j) * N + col] = acc[m][n][j] + bb;
        }
      }
    }
  }
}

// ---------------- repack: normalize q,k (fold scale into q), transpose v ----------------
__global__ __launch_bounds__(256) void k_repack(const u16* __restrict__ QKV,
                                                const float* __restrict__ logit_scale,
                                                u16* __restrict__ Qn, u16* __restrict__ Kn,
                                                u16* __restrict__ Vt) {
  int nt = blockIdx.x;  // 0..31 (64-row tile)
  int h = blockIdx.y;   // 0..15
  int b = blockIdx.z;   // 0..1
  int tid = threadIdx.x;
  int lane = tid & 63, wave = tid >> 6;
  int bh = b * 16 + h;
  float scale = __expf(fminf(logit_scale[h], 4.6051701859880914f));

#pragma unroll 1
  for (int i = 0; i < 16; ++i) {
    int n = nt * 64 + wave * 16 + i;
    size_t off = ((size_t)(b * 2048 + n)) * 3072 + h * 64 + lane;
    float q = bf2f(QKV[off]);
    float k = bf2f(QKV[off + 1024]);
    float sq = q * q, sk = k * k;
#pragma unroll
    for (int d = 1; d < 64; d <<= 1) {
      sq += __shfl_xor(sq, d, 64);
      sk += __shfl_xor(sk, d, 64);
    }
    float rq = scale / fmaxf(sqrtf(sq), 1e-12f);
    float rk = 1.0f / fmaxf(sqrtf(sk), 1e-12f);
    size_t o2 = ((size_t)bh * 2048 + n) * 64 + lane;
    Qn[o2] = f2bf(q * rq);
    Kn[o2] = f2bf(k * rk);
  }

  // V transpose via LDS
  __shared__ u16 lds[64][72];
  int r = tid >> 2, cq = (tid & 3) << 4;
  size_t voff = ((size_t)(b * 2048 + nt * 64 + r)) * 3072 + 2048 + h * 64 + cq;
  *(bf16x8*)&lds[r][cq] = *(const bf16x8*)&QKV[voff];
  *(bf16x8*)&lds[r][cq + 8] = *(const bf16x8*)&QKV[voff + 8];
  __syncthreads();
  int d = tid >> 2, nq = (tid & 3) << 4;
  bf16x8 o0, o1;
#pragma unroll
  for (int i = 0; i < 8; ++i) o0[i] = (short)lds[nq + i][d];
#pragma unroll
  for (int i = 0; i < 8; ++i) o1[i] = (short)lds[nq + 8 + i][d];
  u16* vd = Vt + ((size_t)bh * 64 + d) * 2048 + nt * 64 + nq;
  *(bf16x8*)vd = o0;
  *(bf16x8*)(vd + 8) = o1;
}

// ---------------- flash attention (swapped-QK^T, fixed-max softmax) ----------------
// Per wave: 32 q-rows. S^T = mfma32(K, Q) with acc init = -scale  ->  S - scale <= 0.
// P = __expf(S - scale) in registers; l accumulates lane-locally (no shuffles).
// P -> PV A-fragments via cvt_pk_bf16 + permlane32_swap. O = P V accumulated in regs.
__global__ __launch_bounds__(256, 2) void k_flash(const u16* __restrict__ Qn,
                                                  const u16* __restrict__ Kn,
                                                  const u16* __restrict__ Vt,
                                                  const float* __restrict__ logit_scale,
                                                  u16* __restrict__ AO) {
  __shared__ __align__(16) u16 lsK[2][64 * 64];
  __shared__ __align__(16) u16 lsV[2][64 * 64];
  __shared__ float l_s[4][32];
  int tid = threadIdx.x, lane = tid & 63, wave = tid >> 6;
  int r31 = lane & 31, h = lane >> 5;
  int bh = blockIdx.y, b = bh >> 4, hd = bh & 15;
  int qw = blockIdx.x * 128 + wave * 32;
  const u16* Q = Qn + (size_t)bh * 2048 * 64;
  const u16* Kb = Kn + (size_t)bh * 2048 * 64;
  const u16* Vb = Vt + (size_t)bh * 64 * 2048;

  float scale = __expf(fminf(logit_scale[hd], 4.6051701859880914f));
  float negC = -scale;

  // Q B-fragments: col=lane&31=q, k(d) = 16*ks + 8*h + e
  bf16x8 qB[4];
#pragma unroll
  for (int ks = 0; ks < 4; ++ks)
    qB[ks] = *(const bf16x8*)&Q[(size_t)(qw + r31) * 64 + ks * 16 + h * 8];

  // staging offsets (pre-swizzled global source, linear LDS dest)
  size_t kGO[2], vGO[2];
  int lOff[2];
#pragma unroll
  for (int j = 0; j < 2; ++j) {
    int s = j * 256 + tid;
    int row = s >> 3, ch = s & 7, g = ch ^ (row & 7);
    kGO[j] = (size_t)row * 64 + g * 8;
    vGO[j] = (size_t)row * 2048 + g * 8;
    lOff[j] = s * 8;
  }

  // LDS read offsets (swizzled): rows a*32+r31, chunk (2*ks+h) ^ (r31&7)
  int off[2][4];
#pragma unroll
  for (int a = 0; a < 2; ++a)
#pragma unroll
    for (int ks = 0; ks < 4; ++ks)
      off[a][ks] = (a * 32 + r31) * 64 + ((((ks << 1) | h) ^ (r31 & 7)) << 3);

  f32x16 o0, o1;
#pragma unroll
  for (int i = 0; i < 16; ++i) { o0[i] = 0.f; o1[i] = 0.f; }
  float lsum = 0.f;

  // prologue: stage tile 0
#pragma unroll
  for (int j = 0; j < 2; ++j) {
    gload16(Kb + kGO[j], &lsK[0][lOff[j]]);
    gload16(Vb + vGO[j], &lsV[0][lOff[j]]);
  }
  __syncthreads();

  for (int t = 0; t < 32; ++t) {
    int cur = t & 1;
    if (t < 31) {
      size_t kv0 = (size_t)(t + 1) * 64;
#pragma unroll
      for (int j = 0; j < 2; ++j) {
        gload16(Kb + kv0 * 64 + kGO[j], &lsK[cur ^ 1][lOff[j]]);
        gload16(Vb + kv0 + vGO[j], &lsV[cur ^ 1][lOff[j]]);
      }
    }
    const u16* Kl = lsK[cur];
    const u16* Vl = lsV[cur];

    // S^T = K Q^T - scale   (rows kv, cols q)
    f32x16 s0, s1;
#pragma unroll
    for (int i = 0; i < 16; ++i) { s0[i] = negC; s1[i] = negC; }
#pragma unroll
    for (int ks = 0; ks < 4; ++ks) {
      bf16x8 k0 = *(const bf16x8*)&Kl[off[0][ks]];
      bf16x8 k1 = *(const bf16x8*)&Kl[off[1][ks]];
      s0 = MFMA32(k0, qB[ks], s0);
      s1 = MFMA32(k1, qB[ks], s1);
    }

    // P = exp(S - scale), lane-local l accumulation (no max, no shuffles)
#pragma unroll
    for (int i = 0; i < 16; ++i) {
      float e0 = __expf(s0[i]);
      float e1 = __expf(s1[i]);
      lsum += e0 + e1;
      s0[i] = e0; s1[i] = e1;
    }

    // pack P rows into PV A-fragments: cvt_pk pairs + permlane32 half-swap
    bf16x8 pa[4];
    {
      u32 c0 = cvtpk(s0[0], s0[1]),  c1 = cvtpk(s0[2], s0[3]);
      u32 c2 = cvtpk(s0[4], s0[5]),  c3 = cvtpk(s0[6], s0[7]);
      u32 c4 = cvtpk(s0[8], s0[9]),  c5 = cvtpk(s0[10], s0[11]);
      u32 c6 = cvtpk(s0[12], s0[13]), c7 = cvtpk(s0[14], s0[15]);
      plswap(c0, c2); plswap(c1, c3); plswap(c4, c6); plswap(c5, c7);
      pa[0] = asbf((u32x4){c0, c1, c2, c3});
      pa[1] = asbf((u32x4){c4, c5, c6, c7});
      u32 d0 = cvtpk(s1[0], s1[1]),  d1 = cvtpk(s1[2], s1[3]);
      u32 d2 = cvtpk(s1[4], s1[5]),  d3 = cvtpk(s1[6], s1[7]);
      u32 d4 = cvtpk(s1[8], s1[9]),  d5 = cvtpk(s1[10], s1[11]);
      u32 d6 = cvtpk(s1[12], s1[13]), d7 = cvtpk(s1[14], s1[15]);
      plswap(d0, d2); plswap(d1, d3); plswap(d4, d6); plswap(d5, d7);
      pa[2] = asbf((u32x4){d0, d1, d2, d3});
      pa[3] = asbf((u32x4){d4, d5, d6, d7});
    }

    // O += P V    (A = P[q][kv], B = V[kv][d] read from Vt rows)
#pragma unroll
    for (int ks = 0; ks < 4; ++ks) {
      bf16x8 v0 = *(const bf16x8*)&Vl[off[0][ks]];
      bf16x8 v1 = *(const bf16x8*)&Vl[off[1][ks]];
      o0 = MFMA32(pa[ks], v0, o0);
      o1 = MFMA32(pa[ks], v1, o1);
    }
    __syncthreads();
  }

  // combine l across lane halves; redistribute per-q 1/l via LDS
  float ltot = lsum + __shfl_xor(lsum, 32, 64);
  if (r31 == lane) l_s[wave][r31] = 1.0f / ltot;
  __syncthreads();

#pragma unroll
  for (int r = 0; r < 16; ++r) {
    int cr = (r & 3) + ((r >> 2) << 3) + (h << 2);
    int qr = qw + cr;
    float li = l_s[wave][cr];
    size_t base = ((size_t)(b * 2048 + qr)) * 1024 + hd * 64;
    AO[base + r31] = f2bf(o0[r] * li);
    AO[base + 32 + r31] = f2bf(o1[r] * li);
  }
}

// ---------------- host ----------------
extern "C" void kernel_launch(void* const* d_in, const int* in_sizes, int n_in,
                              void* d_out, int out_size, void* d_ws, size_t ws_size,
                              hipStream_t stream) {
  const float* x = (const float*)d_in[0];
  const float* w_qkv = (const float*)d_in[1];
  const float* w_out = (const float*)d_in[2];
  const float* b_out = (const float*)d_in[3];
  const float* logit_scale = (const float*)d_in[4];

  char* ws = (char*)d_ws;
  u16* Xbf   = (u16*)(ws);                   // 8 MB  [4096][1024]
  u16* Wqkvt = (u16*)(ws + (8ll << 20));     // 6 MB  [3072][1024]
  u16* Woutt = (u16*)(ws + (14ll << 20));    // 2 MB  [1024][1024]
  u16* QKV   = (u16*)(ws + (16ll << 20));    // 24 MB [4096][3072]
  u16* Qn    = (u16*)(ws + (40ll << 20));    // 8 MB  [2][16][2048][64]
  u16* Kn    = (u16*)(ws + (48ll << 20));    // 8 MB
  u16* Vt    = (u16*)(ws + (56ll << 20));    // 8 MB  [2][16][64][2048]
  u16* AO    = Xbf;                          // reuse x-bf16 region [4096][1024]
  float* out = (float*)d_out;

  k_cvt_bf16<<<2048, 256, 0, stream>>>(x, Xbf, 524288);
  k_transpose_bf16<<<dim3(48, 16), 256, 0, stream>>>(w_qkv, Wqkvt, 1024, 3072);
  k_transpose_bf16<<<dim3(16, 16), 256, 0, stream>>>(w_out, Woutt, 1024, 1024);
  k_gemm_bt<true, false><<<dim3(24, 32), 256, 0, stream>>>(Xbf, Wqkvt, QKV, nullptr,
                                                           4096, 3072, 1024);
  k_repack<<<dim3(32, 16, 2), 256, 0, stream>>>(QKV, logit_scale, Qn, Kn, Vt);
  k_flash<<<dim3(16, 32), 256, 0, stream>>>(Qn, Kn, Vt, logit_scale, AO);
  k_gemm_bt<false, true><<<dim3(8, 32), 256, 0, stream>>>(AO, Woutt, out, b_out,
                                                          4096, 1024, 1024);
}